// Round 1
// 2669.877 us; speedup vs baseline: 1.0285x; 1.0285x over previous
//
#include <hip/hip_runtime.h>
#include <hip/hip_bf16.h>
#include <cstdint>

#define AS1 __attribute__((address_space(1)))
#define AS3 __attribute__((address_space(3)))

typedef unsigned short u16;
typedef unsigned int u32;
typedef __bf16 bf16_t;
typedef bf16_t bf16x8 __attribute__((ext_vector_type(8)));
typedef float f32x4 __attribute__((ext_vector_type(4)));

static constexpr int M = 8192;     // 2*4096 tokens
static constexpr int N = 16384;    // output features
static constexpr int K = 4096;     // input features
static constexpr int BM = 128, BN = 128, BK = 32;
static constexpr long long W_ELEMS = (long long)N * K;  // 67108864
static constexpr long long X_ELEMS = (long long)M * K;  // 33554432

__device__ __forceinline__ u16 f32_to_bf16_rne(float f) {
    u32 u = __float_as_uint(f);
    u += 0x7fffu + ((u >> 16) & 1u);
    return (u16)(u >> 16);
}

// ---------------- mean(|w|) reduction: f64 partials + f64 atomic ----------------
__global__ void wabs_sum_kernel(const float* __restrict__ w, double* __restrict__ out) {
    __shared__ double sred[256];
    const float4* w4 = (const float4*)w;
    const int n4 = (int)(W_ELEMS / 4);
    double s = 0.0;
    for (int i = blockIdx.x * blockDim.x + threadIdx.x; i < n4; i += gridDim.x * blockDim.x) {
        float4 v = w4[i];
        s += (double)fabsf(v.x) + (double)fabsf(v.y) + (double)fabsf(v.z) + (double)fabsf(v.w);
    }
    sred[threadIdx.x] = s;
    __syncthreads();
    for (int off = 128; off > 0; off >>= 1) {
        if ((int)threadIdx.x < off) sred[threadIdx.x] += sred[threadIdx.x + off];
        __syncthreads();
    }
    if (threadIdx.x == 0) atomicAdd(out, sred[0]);
}

// ---------------- ternary quantize w -> bf16 {-1,0,1} ----------------
__global__ void w_quant_kernel(const float4* __restrict__ w4, const double* __restrict__ wsum,
                               ushort4* __restrict__ wq) {
    const double scale = fmax(wsum[0] * (1.0 / 67108864.0), 1e-5);
    const double inv = 1.0 / scale;
    const int n4 = (int)(W_ELEMS / 4);
    for (int i = blockIdx.x * blockDim.x + threadIdx.x; i < n4; i += gridDim.x * blockDim.x) {
        float4 v = w4[i];
        float q0 = fminf(fmaxf((float)rint((double)v.x * inv), -1.f), 1.f);
        float q1 = fminf(fmaxf((float)rint((double)v.y * inv), -1.f), 1.f);
        float q2 = fminf(fmaxf((float)rint((double)v.z * inv), -1.f), 1.f);
        float q3 = fminf(fmaxf((float)rint((double)v.w * inv), -1.f), 1.f);
        ushort4 o;
        o.x = f32_to_bf16_rne(q0);
        o.y = f32_to_bf16_rne(q1);
        o.z = f32_to_bf16_rne(q2);
        o.w = f32_to_bf16_rne(q3);
        wq[i] = o;
    }
}

// ---------------- x fp32 -> bf16 (RNE) ----------------
__global__ void x_conv_kernel(const float4* __restrict__ x4, ushort4* __restrict__ xb) {
    const int n4 = (int)(X_ELEMS / 4);
    for (int i = blockIdx.x * blockDim.x + threadIdx.x; i < n4; i += gridDim.x * blockDim.x) {
        float4 v = x4[i];
        ushort4 o;
        o.x = f32_to_bf16_rne(v.x);
        o.y = f32_to_bf16_rne(v.y);
        o.z = f32_to_bf16_rne(v.z);
        o.w = f32_to_bf16_rne(v.w);
        xb[i] = o;
    }
}

// ---------------- async global->LDS, 16B per lane ----------------
__device__ __forceinline__ void gld16(const void* gptr, const void* lptr) {
    __builtin_amdgcn_global_load_lds(
        (AS1 u32*)(uintptr_t)gptr,
        (AS3 u32*)(u32)(uintptr_t)lptr,
        16, 0, 0);
}

// ---------------- GEMM: C[M,N] = A[M,K](bf16) * B[N,K](bf16)^T, fp32 out ----------------
// 128x128 tile, BK=32, 4 waves, 4x4 16x16x32 MFMAs per wave.
// v2: (a) double-buffered LDS + stage-next-while-compute (T3 minimum 2-phase);
//     (b) fragment-order LDS chunks via per-lane pre-swizzled global source
//         (m173 pattern) -> ds_read addr = base + lane*16, conflict-free both sides;
//     (c) bijective XCD-aware block swizzle (T1; 8192 % 8 == 0).
__global__ __launch_bounds__(256) void gemm_bt_kernel(const u16* __restrict__ A,
                                                      const u16* __restrict__ B,
                                                      float* __restrict__ C) {
    // LDS chunk layout per buffer: 8 chunks of 1024B. Chunk c holds rows
    // [c*16, c*16+16) x 32 k. Within a chunk, 16B slot l (= lane) holds
    // row c*16 + (l&15), k-octet (l>>4)*8..+8 -- exactly the MFMA A/B fragment.
    __shared__ __align__(16) u16 sA[2][BM * BK];   // 2 x 8 KiB
    __shared__ __align__(16) u16 sB[2][BN * BK];   // 2 x 8 KiB

    const int tid = threadIdx.x;
    const int wid = tid >> 6;
    const int lane = tid & 63;
    const int fr = lane & 15;   // frag row (A m / B n / C col)
    const int fq = lane >> 4;   // k-octet / C quad

    // XCD-aware bijective swizzle: 8192 blocks, 8 XCDs -> each XCD gets a
    // contiguous 1024-wgid chunk (2 GM=4 bands) so the band's 4MB A-panel
    // stays in its private L2.
    const int bid0 = blockIdx.x;
    const int bid = ((bid0 & 7) << 10) | (bid0 >> 3);

    // band swizzle: GM=4 m-tiles per band, m-fastest within band
    constexpr int GM = 4;
    constexpr int NT = N / BN;  // 128
    const int band = bid / (GM * NT);
    const int r0 = bid % (GM * NT);
    const int m0 = (band * GM + (r0 % GM)) * BM;
    const int n0 = (r0 / GM) * BN;

    // staging (fragment-order): load j in {0,1}, chunk = j*4 + wid,
    // global row = tile + chunk*16 + (lane&15), k-octet = (lane>>4)*8.
    // LDS dest is wave-uniform base; HW adds lane*16.
    const u16* gA0 = A + (size_t)(m0 + wid * 16 + fr) * K + fq * 8;
    const u16* gA1 = gA0 + (size_t)64 * K;
    const u16* gB0 = B + (size_t)(n0 + wid * 16 + fr) * K + fq * 8;
    const u16* gB1 = gB0 + (size_t)64 * K;

    const int wm = (wid & 1) * 64;
    const int wn = (wid >> 1) * 64;
    const int ca = (wm >> 4) * 512;  // u16 offset of this wave's A chunk group
    const int cb = (wn >> 4) * 512;  // u16 offset of this wave's B chunk group

    f32x4 acc[4][4] = {};

    // prologue: stage tile 0 into buffer 0
    gld16(gA0, &sA[0][wid * 512]);
    gld16(gA1, &sA[0][2048 + wid * 512]);
    gld16(gB0, &sB[0][wid * 512]);
    gld16(gB1, &sB[0][2048 + wid * 512]);
    __syncthreads();  // vmcnt(0) drain + barrier: buffer 0 ready

    int cur = 0;
    for (int k0 = 0; k0 < K; k0 += BK) {
        const int nxt = cur ^ 1;
        // stage NEXT K-tile while computing current (loads stay in flight
        // across the ds_read+MFMA phase; drained at the __syncthreads below)
        if (k0 + BK < K) {
            gld16(gA0 + k0 + BK, &sA[nxt][wid * 512]);
            gld16(gA1 + k0 + BK, &sA[nxt][2048 + wid * 512]);
            gld16(gB0 + k0 + BK, &sB[nxt][wid * 512]);
            gld16(gB1 + k0 + BK, &sB[nxt][2048 + wid * 512]);
        }

        bf16x8 a[4], b[4];
#pragma unroll
        for (int mt = 0; mt < 4; ++mt)
            a[mt] = *(const bf16x8*)&sA[cur][ca + mt * 512 + lane * 8];
#pragma unroll
        for (int nt = 0; nt < 4; ++nt)
            b[nt] = *(const bf16x8*)&sB[cur][cb + nt * 512 + lane * 8];
#pragma unroll
        for (int mt = 0; mt < 4; ++mt)
#pragma unroll
            for (int nt = 0; nt < 4; ++nt)
                acc[mt][nt] = __builtin_amdgcn_mfma_f32_16x16x32_bf16(a[mt], b[nt], acc[mt][nt], 0, 0, 0);

        __syncthreads();  // drains vmcnt(0): next buffer staged, cur reads done
        cur = nxt;
    }

    // epilogue: C/D layout col=lane&15, row=(lane>>4)*4+reg
#pragma unroll
    for (int mt = 0; mt < 4; ++mt) {
#pragma unroll
        for (int i = 0; i < 4; ++i) {
            const size_t rrow = (size_t)(m0 + wm + mt * 16 + fq * 4 + i);
            float* Crow = C + rrow * N + n0 + wn + fr;
#pragma unroll
            for (int nt = 0; nt < 4; ++nt)
                Crow[nt * 16] = acc[mt][nt][i];
        }
    }
}

extern "C" void kernel_launch(void* const* d_in, const int* in_sizes, int n_in,
                              void* d_out, int out_size, void* d_ws, size_t ws_size,
                              hipStream_t stream) {
    const float* x = (const float*)d_in[0];
    const float* w = (const float*)d_in[1];
    float* out = (float*)d_out;

    char* ws = (char*)d_ws;
    double* wsum = (double*)ws;                                   // 8 B accumulator
    u16* wq = (u16*)(ws + 256);                                   // 128 MiB bf16 w_q
    u16* xb = (u16*)(ws + 256 + (size_t)W_ELEMS * 2);             // 64 MiB bf16 x

    hipMemsetAsync(wsum, 0, 64, stream);
    wabs_sum_kernel<<<1024, 256, 0, stream>>>(w, wsum);
    w_quant_kernel<<<4096, 256, 0, stream>>>((const float4*)w, wsum, (ushort4*)wq);
    x_conv_kernel<<<2048, 256, 0, stream>>>((const float4*)x, (ushort4*)xb);

    const int nblocks = (M / BM) * (N / BN);  // 8192
    gemm_bt_kernel<<<nblocks, 256, 0, stream>>>(xb, wq, out);
}